// Round 7
// baseline (173.959 us; speedup 1.0000x reference)
//
#include <hip/hip_runtime.h>
#include <math.h>

// Problem constants (from reference setup_inputs)
constexpr int B = 64;
constexpr int T = 1024;
constexpr int C = 128;
constexpr int L = 256;
constexpr int S = 2 * L + 1;     // 513 extended states
constexpr int TRB = 2048;        // transpose blocks (blockIdx >= B)

template <int N> struct IC { static constexpr int value = N; };

// shfl_up by 1 lane as pure VALU DPP (wave_shr:1), bound_ctrl=1 so lane 0
// reads 0 (the CTC halo boundary) without a v_mov-zero of the old operand.
__device__ __forceinline__ float shr1(float x) {
#if __has_builtin(__builtin_amdgcn_mov_dpp)
    return __int_as_float(__builtin_amdgcn_mov_dpp(
        __float_as_int(x), 0x138 /*WAVE_SHR1*/, 0xf, 0xf, true));
#else
    return __int_as_float(__builtin_amdgcn_update_dpp(
        0, __float_as_int(x), 0x138, 0xf, 0xf, true));
#endif
}

// One DPP max-combine stage. bound_ctrl=1: source-less lanes read 0,
// harmless for a max of non-negative alphas.
template <int CTRL>
__device__ __forceinline__ float maxdpp(float x) {
#if __has_builtin(__builtin_amdgcn_mov_dpp)
    float t = __int_as_float(__builtin_amdgcn_mov_dpp(
        __float_as_int(x), CTRL, 0xf, 0xf, true));
#else
    float t = __int_as_float(__builtin_amdgcn_update_dpp(
        0, __float_as_int(x), CTRL, 0xf, 0xf, true));
#endif
    return fmaxf(x, t);
}

// Wave64 max-reduce -> wave-uniform value (readlane 63).
__device__ __forceinline__ float wave_max_dpp(float x) {
    x = maxdpp<0x111>(x);   // row_shr:1
    x = maxdpp<0x112>(x);   // row_shr:2
    x = maxdpp<0x114>(x);   // row_shr:4
    x = maxdpp<0x118>(x);   // row_shr:8
    x = maxdpp<0x142>(x);   // row_bcast:15
    x = maxdpp<0x143>(x);   // row_bcast:31
    return __int_as_float(__builtin_amdgcn_readlane(__float_as_int(x), 63));
}

// 20 scatter global_load_dword as ONE volatile asm block, invisible to the
// compiler's waitcnt pass. R13 discipline: these in-flight destinations
// NEVER cross a basic-block boundary (R12's failure mode: RA phi-copies at
// the back-edge/peel edges read in-flight registers -> garbage -> inf).
__device__ __forceinline__ void fill20(float (&gb)[4], float (&g)[4][4],
                                       int vz, int vc0, int vc1, int vc2,
                                       int vc3, const float* rb) {
    asm volatile(
        "global_load_dword %0, %20, %25 offset:0\n\t"
        "global_load_dword %1, %21, %25 offset:0\n\t"
        "global_load_dword %2, %22, %25 offset:0\n\t"
        "global_load_dword %3, %23, %25 offset:0\n\t"
        "global_load_dword %4, %24, %25 offset:0\n\t"
        "global_load_dword %5, %20, %25 offset:512\n\t"
        "global_load_dword %6, %21, %25 offset:512\n\t"
        "global_load_dword %7, %22, %25 offset:512\n\t"
        "global_load_dword %8, %23, %25 offset:512\n\t"
        "global_load_dword %9, %24, %25 offset:512\n\t"
        "global_load_dword %10, %20, %25 offset:1024\n\t"
        "global_load_dword %11, %21, %25 offset:1024\n\t"
        "global_load_dword %12, %22, %25 offset:1024\n\t"
        "global_load_dword %13, %23, %25 offset:1024\n\t"
        "global_load_dword %14, %24, %25 offset:1024\n\t"
        "global_load_dword %15, %20, %25 offset:1536\n\t"
        "global_load_dword %16, %21, %25 offset:1536\n\t"
        "global_load_dword %17, %22, %25 offset:1536\n\t"
        "global_load_dword %18, %23, %25 offset:1536\n\t"
        "global_load_dword %19, %24, %25 offset:1536"
        : "=&v"(gb[0]), "=&v"(g[0][0]), "=&v"(g[0][1]),
          "=&v"(g[0][2]), "=&v"(g[0][3]),
          "=&v"(gb[1]), "=&v"(g[1][0]), "=&v"(g[1][1]),
          "=&v"(g[1][2]), "=&v"(g[1][3]),
          "=&v"(gb[2]), "=&v"(g[2][0]), "=&v"(g[2][1]),
          "=&v"(g[2][2]), "=&v"(g[2][3]),
          "=&v"(gb[3]), "=&v"(g[3][0]), "=&v"(g[3][1]),
          "=&v"(g[3][2]), "=&v"(g[3][3])
        : "v"(vz), "v"(vc0), "v"(vc1), "v"(vc2), "v"(vc3), "s"(rb));
}

// Fused kernel:
//   blocks [0, B)      : CTC forward, one 64-lane wave per batch element.
//   blocks [B, B+TRB)  : log + transpose, b-major contiguous 16KB reads.
//
// R13: RA-safe counted-vmcnt round. Theory (from R10's VALU-issue-bound
// finding + the invariant ~400cyc/group residual): the compiler's waitcnt
// pass degrades to near-drains each group, exposing a gather latency that
// prefetch distance cannot hide. Test: asm fills + counted s_waitcnt
// vmcnt(20) WITHIN the straight-line 6-group body; ONE vmcnt(0) at body
// end so ZERO loads are in flight across any CFG edge (R12's corruption).
// Fills issue right after the wait, before the group's compute, so the
// body-end drain exposes at most ~1 latency per 24 steps. The remainder
// (<=27 rows) re-reads its rows via plain compiler loads in its own
// blocks -- slower per row but correct by construction (no ring reuse,
// no tail shift machinery).
__global__
__attribute__((amdgpu_waves_per_eu(1, 1)))
__launch_bounds__(64)
void ctc_fused(
    const float* __restrict__ yp,    // [B,T,C] probabilities
    const int*   __restrict__ yt,    // [B,L]
    const int*   __restrict__ il_,   // [B]
    const int*   __restrict__ ll_,   // [B]
    float* __restrict__ out_log,     // [T,B,C]
    float* __restrict__ out_loss)    // scalar, pre-zeroed; atomic mean
{
    const int lane = threadIdx.x;
    if (blockIdx.x >= B) {
        // ---- transpose + log path: one b, 32 consecutive t-rows per block.
        int id = blockIdx.x - B;     // 0..2047
        int bb = id >> 5;            // batch element
        int ck = id & 31;            // which 32-row chunk of T
        const float4* src = (const float4*)yp + ((size_t)bb * T + ck * 32) * 32;
        float4* o4 = (float4*)out_log;
        #pragma unroll
        for (int k = 0; k < 16; ++k) {
            int o = k * 64 + lane;               // 0..1023 (contiguous read)
            float4 v = src[o];
            int tt = ck * 32 + (o >> 5);
            int c4 = o & 31;
            float4 r;
            r.x = __logf(v.x); r.y = __logf(v.y);
            r.z = __logf(v.z); r.w = __logf(v.w);
            o4[((size_t)tt * B + bb) * 32 + c4] = r;
        }
        return;
    }

    // ---- CTC forward path ----
    const int b = blockIdx.x;

    __shared__ float afin[S];     // final alphas for loss extraction

    int il = il_[b]; il = min(max(il, 1), T);
    int ll = ll_[b]; ll = min(max(ll, 1), L);
    const float* yb = yp + (size_t)b * T * C;   // [T,C] slice for this b

    // Labels. Lane owns states 8*lane+k in a[k], k in [0,8] (a[8] is state
    // 8*lane+8, duplicating the next lane's a[0]; needed by lane 63 for
    // state 512). Odd states 8l+1/3/5/7 have labels y4.x/y/z/w.
    int4 y4 = *(const int4*)(yt + b * L + 4 * lane);
    int  pw = yt[b * L + (lane ? 4 * lane - 1 : 0)];  // prev label (lane-1's w)

    // skip-transition gates for the 4 odd states this lane owns.
    float skf4 = (lane && (y4.x != pw))   ? 1.f : 0.f;  // state 8l+1 (s>=3)
    float skf5 = (y4.y != y4.x) ? 1.f : 0.f;            // state 8l+3
    float skf6 = (y4.z != y4.y) ? 1.f : 0.f;            // state 8l+5
    float skf7 = (y4.w != y4.z) ? 1.f : 0.f;            // state 8l+7

    // Byte voffsets for the asm gather loads (VGPRs).
    int vz  = 0;
    int vc0 = y4.x * 4, vc1 = y4.y * 4, vc2 = y4.z * 4, vc3 = y4.w * 4;

    // alpha0 init BEFORE any asm fills: all pre-loop compiler VMEM is
    // issued AND consumed here, so in-loop vmcnt counts only our loads.
    float p00 = yb[0];
    float p0l = yb[y4.x];
    float a[9];
    #pragma unroll
    for (int i = 0; i < 9; ++i) a[i] = 0.f;
    if (lane == 0) { a[0] = p00; a[1] = p0l; }   // alpha0: states 0,1

    // Gather ring: 3 buffers, distance-2 prefetch within the body.
    float gv[3][4][4], gbv[3][4];

    // Fill ring buffer Q with rows r0..r0+3 via the asm block. Single
    // clamp r0 <= T-4 keeps addresses in bounds (over-clamped rows are
    // never consumed: the remainder path re-reads its own rows).
    auto fill = [&](auto Qc, int r0) {
        constexpr int Q = decltype(Qc)::value;
        int r = r0 < T - 4 ? r0 : T - 4;
        const float* rb = yb + (size_t)r * C;
        fill20(gbv[Q], gv[Q], vz, vc0, vc1, vc2, vc3, rb);
    };

    // Counted wait: completes the fill issued 2 groups ago (oldest 20 of
    // <=40 outstanding, FIFO); the newer 20 stay in flight. sched_barrier
    // stops register-only VALU hoisting above the asm wait (rule #18).
    auto wait20 = [&]() {
        asm volatile("s_waitcnt vmcnt(20)");
        __builtin_amdgcn_sched_barrier(0);
    };
    auto wait0 = [&]() {
        asm volatile("s_waitcnt vmcnt(0)");
        __builtin_amdgcn_sched_barrier(0);
    };

    int lsi = 0;           // accumulated log2 scale (exact integer, scalar)
    int t0 = 0;

    // One time step. hh = alpha[8l-1] (prev lane's a[7]) is the ONLY
    // cross-lane input; everything else is lane-local. 1 DPP + 22 VALU.
    auto step = [&](float gb, float g0, float g1, float g2, float g3) {
        float hh = shr1(a[7]);
        float n0 = (a[0] + hh)                      * gb;
        float n1 = fmaf(skf4, hh,   a[1] + a[0])    * g0;
        float n2 = (a[2] + a[1])                    * gb;
        float n3 = fmaf(skf5, a[1], a[3] + a[2])    * g1;
        float n4 = (a[4] + a[3])                    * gb;
        float n5 = fmaf(skf6, a[3], a[5] + a[4])    * g2;
        float n6 = (a[6] + a[5])                    * gb;
        float n7 = fmaf(skf7, a[5], a[7] + a[6])    * g3;
        float n8 = (a[8] + a[7])                    * gb;
        a[0] = n0; a[1] = n1; a[2] = n2; a[3] = n3; a[4] = n4;
        a[5] = n5; a[6] = n6; a[7] = n7; a[8] = n8;
    };

    // One 4-step group inside the body: wait for buffer P's fill (issued
    // 2 groups ago), refill buffer (P+2)%3 immediately (so the body-end
    // drain sees it ~a full compute later), then consume P.
    auto groupW = [&](auto Pc) {
        constexpr int P = decltype(Pc)::value;
        constexpr int F = (P + 2) % 3;
        wait20();
        fill(IC<F>{}, t0 + 9);
        #pragma unroll
        for (int j = 0; j < 4; ++j)
            step(gbv[P][j], gv[P][j][0], gv[P][j][1], gv[P][j][2], gv[P][j][3]);
        t0 += 4;
    };

    // max over the 9 owned states; nested fmaxf triplets fuse to v_max3.
    auto maxw = [&]() {
        float m0 = fmaxf(fmaxf(a[0], a[1]), a[2]);
        float m1 = fmaxf(fmaxf(a[3], a[4]), a[5]);
        float m2 = fmaxf(fmaxf(a[6], a[7]), a[8]);
        return fmaxf(fmaxf(m0, m1), m2);
    };

    // Pipelined rescale: measure (serial DPP tree) after group G, apply
    // (9 exact power-of-2 muls) after G+1; commutes with the linear
    // recurrence, and the DPP chain overlaps the next group's VALU.
    int pinv_bits = 127 << 23;   // pending factor, 1.0f
    int psh = 0;                 // pending log2 adjustment
    auto measure = [&]() {
        float mm = wave_max_dpp(maxw());
        int eb = (__float_as_int(mm) >> 23) & 0xff;
        int sh = 350 - eb;
        sh = sh > 254 ? 254 : (sh < 1 ? 1 : sh);
        pinv_bits = sh << 23;
        psh = sh - 127;
    };
    auto apply = [&]() {
        float inv = __int_as_float(pinv_bits);
        #pragma unroll
        for (int i = 0; i < 9; ++i) a[i] *= inv;
        lsi -= psh;
    };
    auto rescale = [&]() { measure(); apply(); };

    const int full_end = ((il - 1) >> 2) << 2;

    // ---- warm-up: fill b0 (rows 1..4), b1 (rows 5..8), then DRAIN so
    // nothing is in flight across the loop-entry edge.
    fill(IC<0>{}, 1);
    fill(IC<1>{}, 5);
    wait0();

    // Main body: 6 groups (24 steps), counted waits inside, one drain at
    // the end -> zero in-flight registers across the back-edge (RA-safe).
    // apply after even groups, measure after odd (1-group delay; exact).
    while (t0 + 24 <= full_end) {
        groupW(IC<0>{}); apply();
        groupW(IC<1>{}); measure();
        groupW(IC<2>{}); apply();
        groupW(IC<0>{}); measure();
        groupW(IC<1>{}); apply();
        groupW(IC<2>{}); measure();
        wait0();
    }
    apply();                     // drain pending scale

    // ---- remainder: rows t0+1 .. il-1 (<=27), compiler-managed loads,
    // independent of the asm ring (re-reads its rows; no tail machinery).
    while (t0 + 4 <= full_end) {
        const float* rp = yb + (size_t)(t0 + 1) * C;
        float tb4[4], tg4[4][4];
        #pragma unroll
        for (int j = 0; j < 4; ++j) {
            tb4[j]    = rp[j * C];
            tg4[j][0] = rp[j * C + y4.x];
            tg4[j][1] = rp[j * C + y4.y];
            tg4[j][2] = rp[j * C + y4.z];
            tg4[j][3] = rp[j * C + y4.w];
        }
        #pragma unroll
        for (int j = 0; j < 4; ++j)
            step(tb4[j], tg4[j][0], tg4[j][1], tg4[j][2], tg4[j][3]);
        rescale();
        t0 += 4;
    }
    for (int r = t0 + 1; r < il; ++r) {      // <=3 rows
        const float* rp = yb + (size_t)r * C;
        step(rp[0], rp[y4.x], rp[y4.y], rp[y4.z], rp[y4.w]);
    }

    // Loss: -ln(alpha[2ll-1] + alpha[2ll]) with accumulated scale.
    #pragma unroll
    for (int k = 0; k < 8; ++k) afin[8 * lane + k] = a[k];
    if (lane == 63) afin[512] = a[8];
    __syncthreads();
    if (lane == 0) {
        float e1 = afin[2 * ll - 1];
        float e2 = afin[2 * ll];
        float sum = fmaxf(e1 + e2, 1e-37f);
        float loss = -(__log2f(sum) + (float)lsi) * 0.6931471805599453f;  // nats
        atomicAdd(out_loss, loss * (1.0f / (float)B));
    }
}

extern "C" void kernel_launch(void* const* d_in, const int* in_sizes, int n_in,
                              void* d_out, int out_size, void* d_ws, size_t ws_size,
                              hipStream_t stream) {
    const int*   y_true = (const int*)d_in[0];
    const float* y_pred = (const float*)d_in[1];
    const int*   in_len = (const int*)d_in[2];
    const int*   lb_len = (const int*)d_in[3];

    float* out_log  = (float*)d_out;                      // [T,B,C]
    float* out_loss = (float*)d_out + (size_t)T * B * C;  // scalar

    hipMemsetAsync(out_loss, 0, sizeof(float), stream);
    ctc_fused<<<B + TRB, 64, 0, stream>>>(y_pred, y_true, in_len, lb_len,
                                          out_log, out_loss);
}

// Round 8
// 162.770 us; speedup vs baseline: 1.0687x; 1.0687x over previous
//
#include <hip/hip_runtime.h>
#include <math.h>

// Problem constants (from reference setup_inputs)
constexpr int B = 64;
constexpr int T = 1024;
constexpr int C = 128;
constexpr int L = 256;
constexpr int S = 2 * L + 1;     // 513 extended states
constexpr int TRB = 2048;        // transpose blocks (blockIdx >= B)

template <int N> struct IC { static constexpr int value = N; };

// shfl_up by 1 lane as pure VALU DPP (wave_shr:1), bound_ctrl=1 so lane 0
// reads 0 (the CTC halo boundary) without a v_mov-zero of the old operand.
__device__ __forceinline__ float shr1(float x) {
#if __has_builtin(__builtin_amdgcn_mov_dpp)
    return __int_as_float(__builtin_amdgcn_mov_dpp(
        __float_as_int(x), 0x138 /*WAVE_SHR1*/, 0xf, 0xf, true));
#else
    return __int_as_float(__builtin_amdgcn_update_dpp(
        0, __float_as_int(x), 0x138, 0xf, 0xf, true));
#endif
}

// One DPP max-combine stage. bound_ctrl=1: source-less lanes read 0,
// harmless for a max of non-negative alphas.
template <int CTRL>
__device__ __forceinline__ float maxdpp(float x) {
#if __has_builtin(__builtin_amdgcn_mov_dpp)
    float t = __int_as_float(__builtin_amdgcn_mov_dpp(
        __float_as_int(x), CTRL, 0xf, 0xf, true));
#else
    float t = __int_as_float(__builtin_amdgcn_update_dpp(
        0, __float_as_int(x), CTRL, 0xf, 0xf, true));
#endif
    return fmaxf(x, t);
}

// Wave64 max-reduce -> wave-uniform value (readlane 63).
__device__ __forceinline__ float wave_max_dpp(float x) {
    x = maxdpp<0x111>(x);   // row_shr:1
    x = maxdpp<0x112>(x);   // row_shr:2
    x = maxdpp<0x114>(x);   // row_shr:4
    x = maxdpp<0x118>(x);   // row_shr:8
    x = maxdpp<0x142>(x);   // row_bcast:15
    x = maxdpp<0x143>(x);   // row_bcast:31
    return __int_as_float(__builtin_amdgcn_readlane(__float_as_int(x), 63));
}

// R14: one CTC time step as a single hand-scheduled asm block.
// Memory was ruled out (R6/R8/R9/R13 all ~invariant); the residual gap vs
// the 2-cyc-issue floor (~880 vs ~250 cyc/group) is attributed to codegen
// scheduling: the 9 independent state chains must be interleaved so each
// dependent op is ~9 instrs from its producer. Ordering here:
//   DPP(a7) first (a7 was written 9 instrs before block end -> no
//   DPP-read-after-VALU-write hazard, no s_nop), adds descending t8..t0
//   (t0's hh input is 9 instrs after the DPP), 4 fmas, then muls with a7
//   FIRST (so the NEXT step's DPP source is 9 instrs old when read).
// Same op order as the C++ step (add -> fma -> mul), so results match.
__device__ __forceinline__ void step_asm(float (&a)[9], float k4, float k5,
                                         float k6, float k7, float gb,
                                         float g0, float g1, float g2,
                                         float g3) {
    float t0, t1, t2, t3, t4, t5, t6, t7, t8, hh;
    asm volatile(
        "v_mov_b32_dpp %[hh], %[a7] wave_shr:1 row_mask:0xf bank_mask:0xf bound_ctrl:0\n\t"
        "v_add_f32 %[t8], %[a8], %[a7]\n\t"
        "v_add_f32 %[t7], %[a7], %[a6]\n\t"
        "v_add_f32 %[t6], %[a6], %[a5]\n\t"
        "v_add_f32 %[t5], %[a5], %[a4]\n\t"
        "v_add_f32 %[t4], %[a4], %[a3]\n\t"
        "v_add_f32 %[t3], %[a3], %[a2]\n\t"
        "v_add_f32 %[t2], %[a2], %[a1]\n\t"
        "v_add_f32 %[t1], %[a1], %[a0]\n\t"
        "v_add_f32 %[t0], %[a0], %[hh]\n\t"
        "v_fma_f32 %[t7], %[k7], %[a5], %[t7]\n\t"
        "v_fma_f32 %[t5], %[k6], %[a3], %[t5]\n\t"
        "v_fma_f32 %[t3], %[k5], %[a1], %[t3]\n\t"
        "v_fma_f32 %[t1], %[k4], %[hh], %[t1]\n\t"
        "v_mul_f32 %[a7], %[t7], %[g3]\n\t"
        "v_mul_f32 %[a0], %[t0], %[gb]\n\t"
        "v_mul_f32 %[a1], %[t1], %[g0]\n\t"
        "v_mul_f32 %[a2], %[t2], %[gb]\n\t"
        "v_mul_f32 %[a3], %[t3], %[g1]\n\t"
        "v_mul_f32 %[a4], %[t4], %[gb]\n\t"
        "v_mul_f32 %[a5], %[t5], %[g2]\n\t"
        "v_mul_f32 %[a6], %[t6], %[gb]\n\t"
        "v_mul_f32 %[a8], %[t8], %[gb]"
        : [a0]"+v"(a[0]), [a1]"+v"(a[1]), [a2]"+v"(a[2]), [a3]"+v"(a[3]),
          [a4]"+v"(a[4]), [a5]"+v"(a[5]), [a6]"+v"(a[6]), [a7]"+v"(a[7]),
          [a8]"+v"(a[8]),
          [t0]"=&v"(t0), [t1]"=&v"(t1), [t2]"=&v"(t2), [t3]"=&v"(t3),
          [t4]"=&v"(t4), [t5]"=&v"(t5), [t6]"=&v"(t6), [t7]"=&v"(t7),
          [t8]"=&v"(t8), [hh]"=&v"(hh)
        : [k4]"v"(k4), [k5]"v"(k5), [k6]"v"(k6), [k7]"v"(k7),
          [gb]"v"(gb), [g0]"v"(g0), [g1]"v"(g1), [g2]"v"(g2), [g3]"v"(g3));
}

// Fused kernel:
//   blocks [0, B)      : CTC forward, one 64-lane wave per batch element.
//   blocks [B, B+TRB)  : log + transpose, b-major contiguous 16KB reads.
// Structure = R10 (94us, passed) with ONLY the step swapped to step_asm.
__global__
__attribute__((amdgpu_waves_per_eu(1, 1)))
__launch_bounds__(64)
void ctc_fused(
    const float* __restrict__ yp,    // [B,T,C] probabilities
    const int*   __restrict__ yt,    // [B,L]
    const int*   __restrict__ il_,   // [B]
    const int*   __restrict__ ll_,   // [B]
    float* __restrict__ out_log,     // [T,B,C]
    float* __restrict__ out_loss)    // scalar, pre-zeroed; atomic mean
{
    const int lane = threadIdx.x;
    if (blockIdx.x >= B) {
        // ---- transpose + log path: one b, 32 consecutive t-rows per block.
        int id = blockIdx.x - B;     // 0..2047
        int bb = id >> 5;            // batch element
        int ck = id & 31;            // which 32-row chunk of T
        const float4* src = (const float4*)yp + ((size_t)bb * T + ck * 32) * 32;
        float4* o4 = (float4*)out_log;
        #pragma unroll
        for (int k = 0; k < 16; ++k) {
            int o = k * 64 + lane;               // 0..1023 (contiguous read)
            float4 v = src[o];
            int tt = ck * 32 + (o >> 5);
            int c4 = o & 31;
            float4 r;
            r.x = __logf(v.x); r.y = __logf(v.y);
            r.z = __logf(v.z); r.w = __logf(v.w);
            o4[((size_t)tt * B + bb) * 32 + c4] = r;
        }
        return;
    }

    // ---- CTC forward path ----
    const int b = blockIdx.x;

    __shared__ float afin[S];     // final alphas for loss extraction

    int il = il_[b]; il = min(max(il, 1), T);
    int ll = ll_[b]; ll = min(max(ll, 1), L);
    const float* yb = yp + (size_t)b * T * C;   // [T,C] slice for this b

    // Labels. Lane owns states 8*lane+k in a[k], k in [0,8] (a[8] is state
    // 8*lane+8, duplicating the next lane's a[0]; needed by lane 63 for
    // state 512). Odd states 8l+1/3/5/7 have labels y4.x/y/z/w.
    int4 y4 = *(const int4*)(yt + b * L + 4 * lane);
    int  pw = yt[b * L + (lane ? 4 * lane - 1 : 0)];  // prev label (lane-1's w)

    // skip-transition gates for the 4 odd states this lane owns.
    float skf4 = (lane && (y4.x != pw))   ? 1.f : 0.f;  // state 8l+1 (s>=3)
    float skf5 = (y4.y != y4.x) ? 1.f : 0.f;            // state 8l+3
    float skf6 = (y4.z != y4.y) ? 1.f : 0.f;            // state 8l+5
    float skf7 = (y4.w != y4.z) ? 1.f : 0.f;            // state 8l+7

    const int c0 = y4.x, c1 = y4.y, c2 = y4.z, c3 = y4.w;  // own columns

    // Opaque zero voffset: keeps the (lane-uniform-address) blank loads on
    // the VECTOR memory path so one vmcnt discipline covers everything.
    int z0;
    asm volatile("v_mov_b32 %0, 0" : "=v"(z0));

    // Gather ring: 3 buffers, distance-2 prefetch.
    // gv[q][j][*] = own-label probs of ring buffer q, row j; gbv = blank.
    float gv[3][4][4], gbv[3][4];

    // Fill ring buffer Q with rows r0..r0+3. Single clamp r0 <= T-4 keeps
    // all 4 rows in-bounds with one SGPR base + immediate offsets (the
    // clamp only binds for fills whose rows are never consumed as groups;
    // the tail compensates with a +1 slot shift, see tsh below).
    auto fill = [&](auto Qc, int r0) {
        constexpr int Q = decltype(Qc)::value;
        int r = r0 < T - 4 ? r0 : T - 4;
        const float* rb = yb + (size_t)r * C;
        #pragma unroll
        for (int j = 0; j < 4; ++j) {
            gbv[Q][j]   = rb[j * C + z0];
            gv[Q][j][0] = rb[j * C + c0];
            gv[Q][j][1] = rb[j * C + c1];
            gv[Q][j][2] = rb[j * C + c2];
            gv[Q][j][3] = rb[j * C + c3];
        }
    };

    float p00 = yb[0];
    float p0l = yb[c0];

    // ---- warm-up: 2 ring buffers ahead (rows 1..8) ----
    fill(IC<0>{}, 1);
    fill(IC<1>{}, 5);

    float a[9];
    #pragma unroll
    for (int i = 0; i < 9; ++i) a[i] = 0.f;
    if (lane == 0) { a[0] = p00; a[1] = p0l; }   // alpha0: states 0,1

    int lsi = 0;           // accumulated log2 scale (exact integer, scalar)
    int t0 = 0;

    // C++ step for the tail (same op order as step_asm).
    auto step = [&](float gb, float g0, float g1, float g2, float g3) {
        float hh = shr1(a[7]);
        float n0 = (a[0] + hh)                      * gb;
        float n1 = fmaf(skf4, hh,   a[1] + a[0])    * g0;
        float n2 = (a[2] + a[1])                    * gb;
        float n3 = fmaf(skf5, a[1], a[3] + a[2])    * g1;
        float n4 = (a[4] + a[3])                    * gb;
        float n5 = fmaf(skf6, a[3], a[5] + a[4])    * g2;
        float n6 = (a[6] + a[5])                    * gb;
        float n7 = fmaf(skf7, a[5], a[7] + a[6])    * g3;
        float n8 = (a[8] + a[7])                    * gb;
        a[0] = n0; a[1] = n1; a[2] = n2; a[3] = n3; a[4] = n4;
        a[5] = n5; a[6] = n6; a[7] = n7; a[8] = n8;
    };

    // One 4-step group: phase P in {0,1,2}. Consumes ring buffer P,
    // refills buffer (P+2)%3 for group G+2 (distance-2 prefetch).
    auto group = [&](auto Pc) {
        constexpr int P = decltype(Pc)::value;
        constexpr int F = (P + 2) % 3;
        #pragma unroll
        for (int j = 0; j < 4; ++j)
            step_asm(a, skf4, skf5, skf6, skf7,
                     gbv[P][j], gv[P][j][0], gv[P][j][1], gv[P][j][2],
                     gv[P][j][3]);
        fill(IC<F>{}, t0 + 9);
        // Pin this group's loads here; ALU may move freely across.
        __builtin_amdgcn_sched_barrier(0x7);
        t0 += 4;
    };

    // max over the 9 owned states; nested fmaxf triplets fuse to v_max3.
    auto maxw = [&]() {
        float m0 = fmaxf(fmaxf(a[0], a[1]), a[2]);
        float m1 = fmaxf(fmaxf(a[3], a[4]), a[5]);
        float m2 = fmaxf(fmaxf(a[6], a[7]), a[8]);
        return fmaxf(fmaxf(m0, m1), m2);
    };

    // Pipelined rescale: measure (serial DPP tree) after group G, apply
    // (9 exact power-of-2 muls) after G+1; commutes with the linear
    // recurrence, and the DPP chain overlaps the next group's VALU.
    int pinv_bits = 127 << 23;   // pending factor, 1.0f
    int psh = 0;                 // pending log2 adjustment
    auto measure = [&]() {
        float mm = wave_max_dpp(maxw());
        int eb = (__float_as_int(mm) >> 23) & 0xff;
        int sh = 350 - eb;
        sh = sh > 254 ? 254 : (sh < 1 ? 1 : sh);
        pinv_bits = sh << 23;
        psh = sh - 127;
    };
    auto apply = [&]() {
        float inv = __int_as_float(pinv_bits);
        #pragma unroll
        for (int i = 0; i < 9; ++i) a[i] *= inv;
        lsi -= psh;
    };
    auto rescale = [&]() { measure(); apply(); };   // serial form for peels

    const int full_end = ((il - 1) >> 2) << 2;

    // Main body: 6 groups (24 steps) per iteration -- LCM of the 3-phase
    // ring and the 2-group rescale cadence. apply after even groups,
    // measure after odd groups (1-group delay; exact, power-of-2 scale).
    while (t0 + 24 <= full_end) {
        group(IC<0>{});
        apply();
        group(IC<1>{});
        measure();
        group(IC<2>{});
        apply();
        group(IC<0>{});
        measure();
        group(IC<1>{});
        apply();
        group(IC<2>{});
        measure();
    }
    apply();                     // drain pending scale

    // Peeled groups (0..5 remain; phases continue 0,1,2,0,1).
    if (t0 + 4 <= full_end) { group(IC<0>{}); rescale(); }
    if (t0 + 4 <= full_end) { group(IC<1>{}); rescale(); }
    if (t0 + 4 <= full_end) { group(IC<2>{}); rescale(); }
    if (t0 + 4 <= full_end) { group(IC<0>{}); rescale(); }
    if (t0 + 4 <= full_end) { group(IC<1>{}); }

    // Tail: rows full_end+1 .. il-1 (0..3 steps) from buffer (full_end/4)%3.
    // If the fill clamp bound (il >= T-3), rows sit one slot higher.
    const int ph  = (full_end >> 2) % 3;
    const int tsh = (full_end + 1 > T - 4) ? 1 : 0;
    float tg[3][4], tb[3];
    switch (ph) {
    case 0:
        #pragma unroll
        for (int j = 0; j < 3; ++j) { int s_ = j + tsh; tb[j]=gbv[0][s_]; tg[j][0]=gv[0][s_][0]; tg[j][1]=gv[0][s_][1]; tg[j][2]=gv[0][s_][2]; tg[j][3]=gv[0][s_][3]; }
        break;
    case 1:
        #pragma unroll
        for (int j = 0; j < 3; ++j) { int s_ = j + tsh; tb[j]=gbv[1][s_]; tg[j][0]=gv[1][s_][0]; tg[j][1]=gv[1][s_][1]; tg[j][2]=gv[1][s_][2]; tg[j][3]=gv[1][s_][3]; }
        break;
    default:
        #pragma unroll
        for (int j = 0; j < 3; ++j) { int s_ = j + tsh; tb[j]=gbv[2][s_]; tg[j][0]=gv[2][s_][0]; tg[j][1]=gv[2][s_][1]; tg[j][2]=gv[2][s_][2]; tg[j][3]=gv[2][s_][3]; }
        break;
    }
    #pragma unroll
    for (int j = 0; j < 3; ++j) {
        int r = full_end + 1 + j;
        if (r < il)   // uniform branch (il, r wave-uniform)
            step(tb[j], tg[j][0], tg[j][1], tg[j][2], tg[j][3]);
    }

    // Loss: -ln(alpha[2ll-1] + alpha[2ll]) with accumulated scale.
    #pragma unroll
    for (int k = 0; k < 8; ++k) afin[8 * lane + k] = a[k];
    if (lane == 63) afin[512] = a[8];
    __syncthreads();
    if (lane == 0) {
        float e1 = afin[2 * ll - 1];
        float e2 = afin[2 * ll];
        float sum = fmaxf(e1 + e2, 1e-37f);
        float loss = -(__log2f(sum) + (float)lsi) * 0.6931471805599453f;  // nats
        atomicAdd(out_loss, loss * (1.0f / (float)B));
    }
}

extern "C" void kernel_launch(void* const* d_in, const int* in_sizes, int n_in,
                              void* d_out, int out_size, void* d_ws, size_t ws_size,
                              hipStream_t stream) {
    const int*   y_true = (const int*)d_in[0];
    const float* y_pred = (const float*)d_in[1];
    const int*   in_len = (const int*)d_in[2];
    const int*   lb_len = (const int*)d_in[3];

    float* out_log  = (float*)d_out;                      // [T,B,C]
    float* out_loss = (float*)d_out + (size_t)T * B * C;  // scalar

    hipMemsetAsync(out_loss, 0, sizeof(float), stream);
    ctc_fused<<<B + TRB, 64, 0, stream>>>(y_pred, y_true, in_len, lb_len,
                                          out_log, out_loss);
}